// Round 1
// baseline (441.965 us; speedup 1.0000x reference)
//
#include <hip/hip_runtime.h>

#define LRELU_SLOPE 0.2f

// ---------------- block-wide exclusive scan helper (256 threads) -------------
__device__ __forceinline__ int block_excl_scan_256(int v, int* block_total) {
    int lane = threadIdx.x & 63;
    int wid  = threadIdx.x >> 6;
    int x = v;
#pragma unroll
    for (int off = 1; off < 64; off <<= 1) {
        int y = __shfl_up(x, off, 64);
        if (lane >= off) x += y;
    }
    __shared__ int wsum[4];
    if (lane == 63) wsum[wid] = x;
    __syncthreads();
    int t0 = wsum[0], t1 = wsum[1], t2 = wsum[2], t3 = wsum[3];
    int wofs = (wid > 0 ? t0 : 0) + (wid > 1 ? t1 : 0) + (wid > 2 ? t2 : 0);
    if (block_total) *block_total = t0 + t1 + t2 + t3;
    return wofs + x - v;  // exclusive
}

// ---------------- CSR build ----------------
__global__ void k_hist(const int* __restrict__ dst, int* __restrict__ deg, int E) {
    int e = blockIdx.x * 256 + threadIdx.x;
    if (e < E) atomicAdd(&deg[dst[e]], 1);
}

__global__ void k_scan1(const int* __restrict__ deg, int* __restrict__ chunk_excl,
                        int* __restrict__ block_sums, int n) {
    int i = blockIdx.x * 256 + threadIdx.x;
    int v = (i < n) ? deg[i] : 0;
    int total;
    int excl = block_excl_scan_256(v, &total);
    if (i < n) chunk_excl[i] = excl;
    if (threadIdx.x == 0) block_sums[blockIdx.x] = total;
}

__global__ void k_scan2(int* __restrict__ bs, int nb) {
    int i = threadIdx.x;
    int v = (i < (int)nb) ? bs[i] : 0;
    int excl = block_excl_scan_256(v, nullptr);
    if (i < nb) bs[i] = excl;  // each thread rewrites only its own element
}

__global__ void k_scan3(const int* __restrict__ chunk_excl, const int* __restrict__ bs,
                        int* __restrict__ row_ptr, int* __restrict__ cursor, int n, int E) {
    int i = blockIdx.x * 256 + threadIdx.x;
    if (i < n) {
        int r = chunk_excl[i] + bs[blockIdx.x];
        row_ptr[i] = r;
        cursor[i]  = r;
    }
    if (blockIdx.x == 0 && threadIdx.x == 0) row_ptr[n] = E;
}

__global__ void k_scatter(const int* __restrict__ src, const int* __restrict__ dst,
                          int* __restrict__ cursor, int* __restrict__ edge_src, int E) {
    int e = blockIdx.x * 256 + threadIdx.x;
    if (e < E) {
        int d = dst[e];
        int pos = atomicAdd(&cursor[d], 1);
        edge_src[pos] = src[e];
    }
}

// ---------------- h = feature[N,128] @ W[128,64] + b ----------------
// 16 nodes/block; thread = (node r 0..15, col-group cg 0..15 -> 4 cols)
__global__ __launch_bounds__(256) void k_gemm_in(const float* __restrict__ feat,
                                                 const float* __restrict__ W,
                                                 const float* __restrict__ b,
                                                 float* __restrict__ h, int n) {
    __shared__ float WL[128 * 64];
    {
        float4* WL4 = (float4*)WL;
        const float4* W4 = (const float4*)W;
        for (int i = threadIdx.x; i < 128 * 64 / 4; i += 256) WL4[i] = W4[i];
    }
    __syncthreads();
    int node = blockIdx.x * 16 + (threadIdx.x >> 4);
    int cg = (threadIdx.x & 15) * 4;
    if (node >= n) return;
    const float4* fr4 = (const float4*)(feat + (size_t)node * 128);
    float4 acc = *(const float4*)(b + cg);
#pragma unroll 4
    for (int k4 = 0; k4 < 32; ++k4) {
        float4 f = fr4[k4];
        const float* wp = WL + (k4 * 4) * 64 + cg;
        float4 w0 = *(const float4*)(wp);
        float4 w1 = *(const float4*)(wp + 64);
        float4 w2 = *(const float4*)(wp + 128);
        float4 w3 = *(const float4*)(wp + 192);
        acc.x += f.x * w0.x + f.y * w1.x + f.z * w2.x + f.w * w3.x;
        acc.y += f.x * w0.y + f.y * w1.y + f.z * w2.y + f.w * w3.y;
        acc.z += f.x * w0.z + f.y * w1.z + f.z * w2.z + f.w * w3.z;
        acc.w += f.x * w0.w + f.y * w1.w + f.z * w2.w + f.w * w3.w;
    }
    *(float4*)(h + (size_t)node * 64 + cg) = acc;
}

// ---------------- fs = h@Ws+bs, fd = h@Wd+bd (both [64,64]) ----------------
__global__ __launch_bounds__(256) void k_fsfd(const float* __restrict__ h,
                                              const float* __restrict__ Ws, const float* __restrict__ bs,
                                              const float* __restrict__ Wd, const float* __restrict__ bd,
                                              float* __restrict__ fs, float* __restrict__ fd, int n) {
    __shared__ float WsL[64 * 64];
    __shared__ float WdL[64 * 64];
    {
        float4* s4 = (float4*)WsL; float4* d4 = (float4*)WdL;
        const float4* Ws4 = (const float4*)Ws; const float4* Wd4 = (const float4*)Wd;
        for (int i = threadIdx.x; i < 64 * 64 / 4; i += 256) { s4[i] = Ws4[i]; d4[i] = Wd4[i]; }
    }
    __syncthreads();
    int node = blockIdx.x * 16 + (threadIdx.x >> 4);
    int cg = (threadIdx.x & 15) * 4;
    if (node >= n) return;
    const float4* hr4 = (const float4*)(h + (size_t)node * 64);
    float4 aS = *(const float4*)(bs + cg);
    float4 aD = *(const float4*)(bd + cg);
#pragma unroll 4
    for (int k4 = 0; k4 < 16; ++k4) {
        float4 f = hr4[k4];
        const float* sp = WsL + (k4 * 4) * 64 + cg;
        const float* dp = WdL + (k4 * 4) * 64 + cg;
        float4 s0 = *(const float4*)(sp);
        float4 s1 = *(const float4*)(sp + 64);
        float4 s2 = *(const float4*)(sp + 128);
        float4 s3 = *(const float4*)(sp + 192);
        float4 d0 = *(const float4*)(dp);
        float4 d1 = *(const float4*)(dp + 64);
        float4 d2 = *(const float4*)(dp + 128);
        float4 d3 = *(const float4*)(dp + 192);
        aS.x += f.x * s0.x + f.y * s1.x + f.z * s2.x + f.w * s3.x;
        aS.y += f.x * s0.y + f.y * s1.y + f.z * s2.y + f.w * s3.y;
        aS.z += f.x * s0.z + f.y * s1.z + f.z * s2.z + f.w * s3.z;
        aS.w += f.x * s0.w + f.y * s1.w + f.z * s2.w + f.w * s3.w;
        aD.x += f.x * d0.x + f.y * d1.x + f.z * d2.x + f.w * d3.x;
        aD.y += f.x * d0.y + f.y * d1.y + f.z * d2.y + f.w * d3.y;
        aD.z += f.x * d0.z + f.y * d1.z + f.z * d2.z + f.w * d3.z;
        aD.w += f.x * d0.w + f.y * d1.w + f.z * d2.w + f.w * d3.w;
    }
    *(float4*)(fs + (size_t)node * 64 + cg) = aS;
    *(float4*)(fd + (size_t)node * 64 + cg) = aD;
}

// ---------------- GATv2 aggregate: one wave per dst node ----------------
// lane = head*16 + d. Per edge: coalesced 256B gather of fs[src] row,
// per-head dot via 4x shfl_xor, online sum of p and p*fs. relu(acc/s).
__global__ __launch_bounds__(256) void k_agg(const float* __restrict__ fs,
                                             const float* __restrict__ fd,
                                             const float* __restrict__ attn,  // 64 floats (this layer)
                                             const int* __restrict__ row_ptr,
                                             const int* __restrict__ edge_src,
                                             float* __restrict__ hout, int n) {
    int wid = threadIdx.x >> 6;
    int node = blockIdx.x * 4 + wid;
    if (node >= n) return;
    int lane = threadIdx.x & 63;
    float a   = attn[lane];
    float fdv = fd[(size_t)node * 64 + lane];
    int s0 = row_ptr[node], s1 = row_ptr[node + 1];
    float ssum = 0.f, acc = 0.f;
    int sidx = (s0 < s1) ? edge_src[s0] : 0;
    for (int e = s0; e < s1; ++e) {
        int nsidx = (e + 1 < s1) ? edge_src[e + 1] : 0;  // prefetch next src id
        float fsv = fs[(size_t)sidx * 64 + lane];
        float t = fsv + fdv;
        t = (t > 0.f) ? t : LRELU_SLOPE * t;
        t *= a;
        // reduce over d (16 lanes within each head group)
        t += __shfl_xor(t, 1, 64);
        t += __shfl_xor(t, 2, 64);
        t += __shfl_xor(t, 4, 64);
        t += __shfl_xor(t, 8, 64);
        float p = __expf(t);
        ssum += p;
        acc += p * fsv;
        sidx = nsidx;
    }
    float o = (s1 > s0) ? (acc / ssum) : 0.f;
    o = fmaxf(o, 0.f);
    hout[(size_t)node * 64 + lane] = o;
}

// ---------------- logits = h[N,64] @ W_out[64,2] + b_out ----------------
__global__ void k_out(const float* __restrict__ h, const float* __restrict__ Wo,
                      const float* __restrict__ bo, float* __restrict__ out, int n) {
    int i = blockIdx.x * 256 + threadIdx.x;
    if (i >= n * 2) return;
    int node = i >> 1, c = i & 1;
    const float* hr = h + (size_t)node * 64;
    float acc = bo[c];
#pragma unroll 8
    for (int k = 0; k < 64; ++k) acc += hr[k] * Wo[k * 2 + c];
    out[i] = acc;
}

extern "C" void kernel_launch(void* const* d_in, const int* in_sizes, int n_in,
                              void* d_out, int out_size, void* d_ws, size_t ws_size,
                              hipStream_t stream) {
    const float* feature  = (const float*)d_in[0];
    const int*   src      = (const int*)d_in[1];
    const int*   dst      = (const int*)d_in[2];
    const float* W_in     = (const float*)d_in[3];
    const float* b_in     = (const float*)d_in[4];
    const float* fc_src_W = (const float*)d_in[5];
    const float* fc_src_b = (const float*)d_in[6];
    const float* fc_dst_W = (const float*)d_in[7];
    const float* fc_dst_b = (const float*)d_in[8];
    const float* attn     = (const float*)d_in[9];
    const float* W_out    = (const float*)d_in[10];
    const float* b_out    = (const float*)d_in[11];
    float* out = (float*)d_out;

    const int N = in_sizes[0] / 128;  // 50000
    const int E = in_sizes[1];        // 800000
    const int nb = (N + 255) / 256;   // scan blocks (196 <= 256)

    // workspace layout (256B-aligned slices)
    char* ws = (char*)d_ws;
    size_t off = 0;
    auto take = [&](size_t bytes) { char* p = ws + off; off = (off + bytes + 255) & ~(size_t)255; return p; };
    int*   deg        = (int*)take((size_t)N * 4);
    int*   row_ptr    = (int*)take((size_t)(N + 1) * 4);
    int*   cursor     = (int*)take((size_t)N * 4);
    int*   block_sums = (int*)take((size_t)nb * 4);
    int*   edge_src   = (int*)take((size_t)E * 4);
    float* h          = (float*)take((size_t)N * 64 * 4);
    float* fs         = (float*)take((size_t)N * 64 * 4);
    float* fd         = (float*)take((size_t)N * 64 * 4);
    (void)ws_size; (void)n_in; (void)out_size;

    const int eb = (E + 255) / 256;
    const int gemm_blocks = (N + 15) / 16;
    const int agg_blocks  = (N + 3) / 4;

    // ---- CSR build (dst-sorted) ----
    hipMemsetAsync(deg, 0, (size_t)N * 4, stream);
    k_hist<<<eb, 256, 0, stream>>>(dst, deg, E);
    k_scan1<<<nb, 256, 0, stream>>>(deg, cursor /*chunk_excl temp*/, block_sums, N);
    k_scan2<<<1, 256, 0, stream>>>(block_sums, nb);
    k_scan3<<<nb, 256, 0, stream>>>(cursor, block_sums, row_ptr, cursor, N, E);
    k_scatter<<<eb, 256, 0, stream>>>(src, dst, cursor, edge_src, E);

    // ---- input projection ----
    k_gemm_in<<<gemm_blocks, 256, 0, stream>>>(feature, W_in, b_in, h, N);

    // ---- 2 GATv2 layers ----
    for (int l = 0; l < 2; ++l) {
        k_fsfd<<<gemm_blocks, 256, 0, stream>>>(h, fc_src_W + l * 4096, fc_src_b + l * 64,
                                                fc_dst_W + l * 4096, fc_dst_b + l * 64,
                                                fs, fd, N);
        k_agg<<<agg_blocks, 256, 0, stream>>>(fs, fd, attn + l * 64, row_ptr, edge_src, h, N);
    }

    // ---- output projection ----
    k_out<<<(N * 2 + 255) / 256, 256, 0, stream>>>(h, W_out, b_out, out, N);
}

// Round 2
// 348.422 us; speedup vs baseline: 1.2685x; 1.2685x over previous
//
#include <hip/hip_runtime.h>

#define LRELU_SLOPE 0.2f

// ---------------- DPP 16-lane (per-head) all-reduce sum ----------------
// row_ror:n on CDNA rotates within each 16-lane row; offsets 8/4/2/1 give a
// rotate-allreduce where every lane holds the 16-lane sum. VALU pipe (fast),
// unlike __shfl_xor which lowers to ds_swizzle (LDS pipe latency).
template <int CTRL>
__device__ __forceinline__ float dpp_add(float x) {
    int xi = __float_as_int(x);
    int yi = __builtin_amdgcn_update_dpp(xi, xi, CTRL, 0xF, 0xF, false);
    return x + __int_as_float(yi);
}
__device__ __forceinline__ float reduce16(float t) {
    t = dpp_add<0x128>(t);  // row_ror:8
    t = dpp_add<0x124>(t);  // row_ror:4
    t = dpp_add<0x122>(t);  // row_ror:2
    t = dpp_add<0x121>(t);  // row_ror:1
    return t;
}

// ---------------- block-wide exclusive scan helper (256 threads) -------------
__device__ __forceinline__ int block_excl_scan_256(int v, int* block_total) {
    int lane = threadIdx.x & 63;
    int wid  = threadIdx.x >> 6;
    int x = v;
#pragma unroll
    for (int off = 1; off < 64; off <<= 1) {
        int y = __shfl_up(x, off, 64);
        if (lane >= off) x += y;
    }
    __shared__ int wsum[4];
    if (lane == 63) wsum[wid] = x;
    __syncthreads();
    int t0 = wsum[0], t1 = wsum[1], t2 = wsum[2], t3 = wsum[3];
    int wofs = (wid > 0 ? t0 : 0) + (wid > 1 ? t1 : 0) + (wid > 2 ? t2 : 0);
    if (block_total) *block_total = t0 + t1 + t2 + t3;
    return wofs + x - v;  // exclusive
}

// ---------------- CSR build ----------------
__global__ void k_hist(const int* __restrict__ dst, int* __restrict__ deg, int E) {
    int e = blockIdx.x * 256 + threadIdx.x;
    if (e < E) atomicAdd(&deg[dst[e]], 1);
}

__global__ void k_scan1(const int* __restrict__ deg, int* __restrict__ chunk_excl,
                        int* __restrict__ block_sums, int n) {
    int i = blockIdx.x * 256 + threadIdx.x;
    int v = (i < n) ? deg[i] : 0;
    int total;
    int excl = block_excl_scan_256(v, &total);
    if (i < n) chunk_excl[i] = excl;
    if (threadIdx.x == 0) block_sums[blockIdx.x] = total;
}

__global__ void k_scan2(int* __restrict__ bs, int nb) {
    int i = threadIdx.x;
    int v = (i < (int)nb) ? bs[i] : 0;
    int excl = block_excl_scan_256(v, nullptr);
    if (i < nb) bs[i] = excl;  // each thread rewrites only its own element
}

__global__ void k_scan3(const int* __restrict__ chunk_excl, const int* __restrict__ bs,
                        int* __restrict__ row_ptr, int* __restrict__ cursor, int n, int E) {
    int i = blockIdx.x * 256 + threadIdx.x;
    if (i < n) {
        int r = chunk_excl[i] + bs[blockIdx.x];
        row_ptr[i] = r;
        cursor[i]  = r;
    }
    if (blockIdx.x == 0 && threadIdx.x == 0) row_ptr[n] = E;
}

__global__ void k_scatter(const int* __restrict__ src, const int* __restrict__ dst,
                          int* __restrict__ cursor, int* __restrict__ edge_src, int E) {
    int e = blockIdx.x * 256 + threadIdx.x;
    if (e < E) {
        int d = dst[e];
        int pos = atomicAdd(&cursor[d], 1);
        edge_src[pos] = src[e];
    }
}

// ---------------- h = feature[N,128] @ W[128,64] + b ----------------
__global__ __launch_bounds__(256) void k_gemm_in(const float* __restrict__ feat,
                                                 const float* __restrict__ W,
                                                 const float* __restrict__ b,
                                                 float* __restrict__ h, int n) {
    __shared__ float WL[128 * 64];
    {
        float4* WL4 = (float4*)WL;
        const float4* W4 = (const float4*)W;
        for (int i = threadIdx.x; i < 128 * 64 / 4; i += 256) WL4[i] = W4[i];
    }
    __syncthreads();
    int node = blockIdx.x * 16 + (threadIdx.x >> 4);
    int cg = (threadIdx.x & 15) * 4;
    if (node >= n) return;
    const float4* fr4 = (const float4*)(feat + (size_t)node * 128);
    float4 acc = *(const float4*)(b + cg);
#pragma unroll 4
    for (int k4 = 0; k4 < 32; ++k4) {
        float4 f = fr4[k4];
        const float* wp = WL + (k4 * 4) * 64 + cg;
        float4 w0 = *(const float4*)(wp);
        float4 w1 = *(const float4*)(wp + 64);
        float4 w2 = *(const float4*)(wp + 128);
        float4 w3 = *(const float4*)(wp + 192);
        acc.x += f.x * w0.x + f.y * w1.x + f.z * w2.x + f.w * w3.x;
        acc.y += f.x * w0.y + f.y * w1.y + f.z * w2.y + f.w * w3.y;
        acc.z += f.x * w0.z + f.y * w1.z + f.z * w2.z + f.w * w3.z;
        acc.w += f.x * w0.w + f.y * w1.w + f.z * w2.w + f.w * w3.w;
    }
    *(float4*)(h + (size_t)node * 64 + cg) = acc;
}

// ---------------- fs = h@Ws+bs, fd = h@Wd+bd (both [64,64]) ----------------
__global__ __launch_bounds__(256) void k_fsfd(const float* __restrict__ h,
                                              const float* __restrict__ Ws, const float* __restrict__ bs,
                                              const float* __restrict__ Wd, const float* __restrict__ bd,
                                              float* __restrict__ fs, float* __restrict__ fd, int n) {
    __shared__ float WsL[64 * 64];
    __shared__ float WdL[64 * 64];
    {
        float4* s4 = (float4*)WsL; float4* d4 = (float4*)WdL;
        const float4* Ws4 = (const float4*)Ws; const float4* Wd4 = (const float4*)Wd;
        for (int i = threadIdx.x; i < 64 * 64 / 4; i += 256) { s4[i] = Ws4[i]; d4[i] = Wd4[i]; }
    }
    __syncthreads();
    int node = blockIdx.x * 16 + (threadIdx.x >> 4);
    int cg = (threadIdx.x & 15) * 4;
    if (node >= n) return;
    const float4* hr4 = (const float4*)(h + (size_t)node * 64);
    float4 aS = *(const float4*)(bs + cg);
    float4 aD = *(const float4*)(bd + cg);
#pragma unroll 4
    for (int k4 = 0; k4 < 16; ++k4) {
        float4 f = hr4[k4];
        const float* sp = WsL + (k4 * 4) * 64 + cg;
        const float* dp = WdL + (k4 * 4) * 64 + cg;
        float4 s0 = *(const float4*)(sp);
        float4 s1 = *(const float4*)(sp + 64);
        float4 s2 = *(const float4*)(sp + 128);
        float4 s3 = *(const float4*)(sp + 192);
        float4 d0 = *(const float4*)(dp);
        float4 d1 = *(const float4*)(dp + 64);
        float4 d2 = *(const float4*)(dp + 128);
        float4 d3 = *(const float4*)(dp + 192);
        aS.x += f.x * s0.x + f.y * s1.x + f.z * s2.x + f.w * s3.x;
        aS.y += f.x * s0.y + f.y * s1.y + f.z * s2.y + f.w * s3.y;
        aS.z += f.x * s0.z + f.y * s1.z + f.z * s2.z + f.w * s3.z;
        aS.w += f.x * s0.w + f.y * s1.w + f.z * s2.w + f.w * s3.w;
        aD.x += f.x * d0.x + f.y * d1.x + f.z * d2.x + f.w * d3.x;
        aD.y += f.x * d0.y + f.y * d1.y + f.z * d2.y + f.w * d3.y;
        aD.z += f.x * d0.z + f.y * d1.z + f.z * d2.z + f.w * d3.z;
        aD.w += f.x * d0.w + f.y * d1.w + f.z * d2.w + f.w * d3.w;
    }
    *(float4*)(fs + (size_t)node * 64 + cg) = aS;
    *(float4*)(fd + (size_t)node * 64 + cg) = aD;
}

// ---------------- GATv2 aggregate: one wave per dst node ----------------
// lane = head*16 + d. Batch-8 pipeline: issue 8 id loads, 8 fs-row gathers,
// then 8 independent DPP-reduce score chains. Amortizes gather latency 8x.
__global__ __launch_bounds__(256) void k_agg(const float* __restrict__ fs,
                                             const float* __restrict__ fd,
                                             const float* __restrict__ attn,  // 64 floats (this layer)
                                             const int* __restrict__ row_ptr,
                                             const int* __restrict__ edge_src,
                                             float* __restrict__ hout, int n) {
    int wid = threadIdx.x >> 6;
    int node = blockIdx.x * 4 + wid;
    if (node >= n) return;
    int lane = threadIdx.x & 63;
    float a   = attn[lane];
    float fdv = fd[(size_t)node * 64 + lane];
    int s0 = row_ptr[node], s1 = row_ptr[node + 1];
    float ssum = 0.f, acc = 0.f;
    for (int base = s0; base < s1; base += 8) {
        int ids[8];
#pragma unroll
        for (int k = 0; k < 8; ++k) {
            int ee = base + k;
            ids[k] = edge_src[ee < s1 ? ee : s1 - 1];  // clamp: safe dup of last edge
        }
        float fv[8];
#pragma unroll
        for (int k = 0; k < 8; ++k)
            fv[k] = fs[(size_t)ids[k] * 64 + lane];
#pragma unroll
        for (int k = 0; k < 8; ++k) {
            float t = fv[k] + fdv;
            t = (t > 0.f) ? t : LRELU_SLOPE * t;
            t *= a;
            t = reduce16(t);            // per-head sum, all lanes get it
            float p = __expf(t);
            p = (base + k < s1) ? p : 0.f;  // mask tail duplicates
            ssum += p;
            acc = fmaf(p, fv[k], acc);
        }
    }
    float o = (s1 > s0) ? (acc / ssum) : 0.f;
    hout[(size_t)node * 64 + lane] = fmaxf(o, 0.f);
}

// ---------------- logits = h[N,64] @ W_out[64,2] + b_out ----------------
__global__ void k_out(const float* __restrict__ h, const float* __restrict__ Wo,
                      const float* __restrict__ bo, float* __restrict__ out, int n) {
    int i = blockIdx.x * 256 + threadIdx.x;
    if (i >= n * 2) return;
    int node = i >> 1, c = i & 1;
    const float* hr = h + (size_t)node * 64;
    float acc = bo[c];
#pragma unroll 8
    for (int k = 0; k < 64; ++k) acc += hr[k] * Wo[k * 2 + c];
    out[i] = acc;
}

extern "C" void kernel_launch(void* const* d_in, const int* in_sizes, int n_in,
                              void* d_out, int out_size, void* d_ws, size_t ws_size,
                              hipStream_t stream) {
    const float* feature  = (const float*)d_in[0];
    const int*   src      = (const int*)d_in[1];
    const int*   dst      = (const int*)d_in[2];
    const float* W_in     = (const float*)d_in[3];
    const float* b_in     = (const float*)d_in[4];
    const float* fc_src_W = (const float*)d_in[5];
    const float* fc_src_b = (const float*)d_in[6];
    const float* fc_dst_W = (const float*)d_in[7];
    const float* fc_dst_b = (const float*)d_in[8];
    const float* attn     = (const float*)d_in[9];
    const float* W_out    = (const float*)d_in[10];
    const float* b_out    = (const float*)d_in[11];
    float* out = (float*)d_out;

    const int N = in_sizes[0] / 128;  // 50000
    const int E = in_sizes[1];        // 800000
    const int nb = (N + 255) / 256;   // scan blocks (196 <= 256)

    // workspace layout (256B-aligned slices)
    char* ws = (char*)d_ws;
    size_t off = 0;
    auto take = [&](size_t bytes) { char* p = ws + off; off = (off + bytes + 255) & ~(size_t)255; return p; };
    int*   deg        = (int*)take((size_t)N * 4);
    int*   row_ptr    = (int*)take((size_t)(N + 1) * 4);
    int*   cursor     = (int*)take((size_t)N * 4);
    int*   block_sums = (int*)take((size_t)nb * 4);
    int*   edge_src   = (int*)take((size_t)E * 4);
    float* h          = (float*)take((size_t)N * 64 * 4);
    float* fs         = (float*)take((size_t)N * 64 * 4);
    float* fd         = (float*)take((size_t)N * 64 * 4);
    (void)ws_size; (void)n_in; (void)out_size;

    const int eb = (E + 255) / 256;
    const int gemm_blocks = (N + 15) / 16;
    const int agg_blocks  = (N + 3) / 4;

    // ---- CSR build (dst-sorted) ----
    hipMemsetAsync(deg, 0, (size_t)N * 4, stream);
    k_hist<<<eb, 256, 0, stream>>>(dst, deg, E);
    k_scan1<<<nb, 256, 0, stream>>>(deg, cursor /*chunk_excl temp*/, block_sums, N);
    k_scan2<<<1, 256, 0, stream>>>(block_sums, nb);
    k_scan3<<<nb, 256, 0, stream>>>(cursor, block_sums, row_ptr, cursor, N, E);
    k_scatter<<<eb, 256, 0, stream>>>(src, dst, cursor, edge_src, E);

    // ---- input projection ----
    k_gemm_in<<<gemm_blocks, 256, 0, stream>>>(feature, W_in, b_in, h, N);

    // ---- 2 GATv2 layers ----
    for (int l = 0; l < 2; ++l) {
        k_fsfd<<<gemm_blocks, 256, 0, stream>>>(h, fc_src_W + l * 4096, fc_src_b + l * 64,
                                                fc_dst_W + l * 4096, fc_dst_b + l * 64,
                                                fs, fd, N);
        k_agg<<<agg_blocks, 256, 0, stream>>>(fs, fd, attn + l * 64, row_ptr, edge_src, h, N);
    }

    // ---- output projection ----
    k_out<<<(N * 2 + 255) / 256, 256, 0, stream>>>(h, W_out, b_out, out, N);
}

// Round 3
// 286.960 us; speedup vs baseline: 1.5402x; 1.2142x over previous
//
#include <hip/hip_runtime.h>

#define LRELU_SLOPE 0.2f

// ---------------- DPP 16-lane (per-head) all-reduce sum ----------------
template <int CTRL>
__device__ __forceinline__ float dpp_add(float x) {
    int xi = __float_as_int(x);
    int yi = __builtin_amdgcn_update_dpp(xi, xi, CTRL, 0xF, 0xF, false);
    return x + __int_as_float(yi);
}
__device__ __forceinline__ float reduce16(float t) {
    t = dpp_add<0x128>(t);  // row_ror:8
    t = dpp_add<0x124>(t);  // row_ror:4
    t = dpp_add<0x122>(t);  // row_ror:2
    t = dpp_add<0x121>(t);  // row_ror:1
    return t;
}

// ---------------- block-wide exclusive scan helper (256 threads) -------------
__device__ __forceinline__ int block_excl_scan_256(int v, int* block_total) {
    int lane = threadIdx.x & 63;
    int wid  = threadIdx.x >> 6;
    int x = v;
#pragma unroll
    for (int off = 1; off < 64; off <<= 1) {
        int y = __shfl_up(x, off, 64);
        if (lane >= off) x += y;
    }
    __shared__ int wsum[4];
    if (lane == 63) wsum[wid] = x;
    __syncthreads();
    int t0 = wsum[0], t1 = wsum[1], t2 = wsum[2], t3 = wsum[3];
    int wofs = (wid > 0 ? t0 : 0) + (wid > 1 ? t1 : 0) + (wid > 2 ? t2 : 0);
    if (block_total) *block_total = t0 + t1 + t2 + t3;
    return wofs + x - v;  // exclusive
}

// role split for fused kernels: interleave A/B blocks by parity
__device__ __forceinline__ void role_split(int bid, int gA, int gB, bool& isA, int& idx) {
    int m = (gA < gB ? gA : gB) * 2;
    if (bid < m) { isA = (bid & 1) == 0; idx = bid >> 1; }
    else         { isA = (gA > gB);      idx = (m >> 1) + (bid - m); }
}

// ---------------- scans ----------------
__global__ void k_scan1(const int* __restrict__ deg, int* __restrict__ chunk_excl,
                        int* __restrict__ block_sums, int n) {
    int i = blockIdx.x * 256 + threadIdx.x;
    int v = (i < n) ? deg[i] : 0;
    int total;
    int excl = block_excl_scan_256(v, &total);
    if (i < n) chunk_excl[i] = excl;
    if (threadIdx.x == 0) block_sums[blockIdx.x] = total;
}

__global__ void k_scan2(int* __restrict__ bs, int nb) {
    int i = threadIdx.x;
    int v = (i < nb) ? bs[i] : 0;
    int excl = block_excl_scan_256(v, nullptr);
    if (i < nb) bs[i] = excl;
}

__global__ void k_scan3(const int* __restrict__ chunk_excl, const int* __restrict__ bs,
                        int* __restrict__ row_ptr, int* __restrict__ cursor,
                        int* __restrict__ edge_src, int n, int E) {
    int i = blockIdx.x * 256 + threadIdx.x;
    if (i < n) {
        int r = chunk_excl[i] + bs[blockIdx.x];
        row_ptr[i] = r;
        cursor[i]  = r;
    }
    if (blockIdx.x == 0 && threadIdx.x == 0) row_ptr[n] = E;
    // zero the 64-int pad past edge_src[E] so k_agg's unguarded batch reads
    // always yield a valid (maskable) src id
    if (blockIdx.x == 0 && threadIdx.x < 64) edge_src[E + threadIdx.x] = 0;
}

// ---------------- FUSED: hist (atomics, memory pipe) + gemm_in (VALU) --------
// h = feature[N,128] @ W[128,64] + b   ||   deg[dst[e]]++
__global__ __launch_bounds__(256) void k_hist_gemm(
        const int* __restrict__ dst, int* __restrict__ deg, int E, int g_hist,
        const float* __restrict__ feat, const float* __restrict__ W,
        const float* __restrict__ b, float* __restrict__ h, int n, int g_gemm) {
    bool isA; int idx;
    role_split(blockIdx.x, g_hist, g_gemm, isA, idx);
    if (isA) {
        int e = idx * 256 + threadIdx.x;
        if (e < E) atomicAdd(&deg[dst[e]], 1);
        return;
    }
    __shared__ float WL[128 * 64];
    {
        float4* WL4 = (float4*)WL;
        const float4* W4 = (const float4*)W;
        for (int i = threadIdx.x; i < 128 * 64 / 4; i += 256) WL4[i] = W4[i];
    }
    __syncthreads();
    int node = idx * 16 + (threadIdx.x >> 4);
    int cg = (threadIdx.x & 15) * 4;
    if (node >= n) return;
    const float4* fr4 = (const float4*)(feat + (size_t)node * 128);
    float4 acc = *(const float4*)(b + cg);
#pragma unroll 4
    for (int k4 = 0; k4 < 32; ++k4) {
        float4 f = fr4[k4];
        const float* wp = WL + (k4 * 4) * 64 + cg;
        float4 w0 = *(const float4*)(wp);
        float4 w1 = *(const float4*)(wp + 64);
        float4 w2 = *(const float4*)(wp + 128);
        float4 w3 = *(const float4*)(wp + 192);
        acc.x += f.x * w0.x + f.y * w1.x + f.z * w2.x + f.w * w3.x;
        acc.y += f.x * w0.y + f.y * w1.y + f.z * w2.y + f.w * w3.y;
        acc.z += f.x * w0.z + f.y * w1.z + f.z * w2.z + f.w * w3.z;
        acc.w += f.x * w0.w + f.y * w1.w + f.z * w2.w + f.w * w3.w;
    }
    *(float4*)(h + (size_t)node * 64 + cg) = acc;
}

// fsfd inner body (shared by fused + standalone kernels)
__device__ __forceinline__ void fsfd_body(
        const float* __restrict__ h,
        const float* __restrict__ Ws, const float* __restrict__ bs,
        const float* __restrict__ Wd, const float* __restrict__ bd,
        float* __restrict__ fs, float* __restrict__ fd, int n, int idx,
        float* WsL, float* WdL) {
    {
        float4* s4 = (float4*)WsL; float4* d4 = (float4*)WdL;
        const float4* Ws4 = (const float4*)Ws; const float4* Wd4 = (const float4*)Wd;
        for (int i = threadIdx.x; i < 64 * 64 / 4; i += 256) { s4[i] = Ws4[i]; d4[i] = Wd4[i]; }
    }
    __syncthreads();
    int node = idx * 16 + (threadIdx.x >> 4);
    int cg = (threadIdx.x & 15) * 4;
    if (node >= n) return;
    const float4* hr4 = (const float4*)(h + (size_t)node * 64);
    float4 aS = *(const float4*)(bs + cg);
    float4 aD = *(const float4*)(bd + cg);
#pragma unroll 4
    for (int k4 = 0; k4 < 16; ++k4) {
        float4 f = hr4[k4];
        const float* sp = WsL + (k4 * 4) * 64 + cg;
        const float* dp = WdL + (k4 * 4) * 64 + cg;
        float4 s0 = *(const float4*)(sp);
        float4 s1 = *(const float4*)(sp + 64);
        float4 s2 = *(const float4*)(sp + 128);
        float4 s3 = *(const float4*)(sp + 192);
        float4 d0 = *(const float4*)(dp);
        float4 d1 = *(const float4*)(dp + 64);
        float4 d2 = *(const float4*)(dp + 128);
        float4 d3 = *(const float4*)(dp + 192);
        aS.x += f.x * s0.x + f.y * s1.x + f.z * s2.x + f.w * s3.x;
        aS.y += f.x * s0.y + f.y * s1.y + f.z * s2.y + f.w * s3.y;
        aS.z += f.x * s0.z + f.y * s1.z + f.z * s2.z + f.w * s3.z;
        aS.w += f.x * s0.w + f.y * s1.w + f.z * s2.w + f.w * s3.w;
        aD.x += f.x * d0.x + f.y * d1.x + f.z * d2.x + f.w * d3.x;
        aD.y += f.x * d0.y + f.y * d1.y + f.z * d2.y + f.w * d3.y;
        aD.z += f.x * d0.z + f.y * d1.z + f.z * d2.z + f.w * d3.z;
        aD.w += f.x * d0.w + f.y * d1.w + f.z * d2.w + f.w * d3.w;
    }
    *(float4*)(fs + (size_t)node * 64 + cg) = aS;
    *(float4*)(fd + (size_t)node * 64 + cg) = aD;
}

// ---------------- FUSED: scatter (atomics) + fsfd layer 0 (VALU) ------------
__global__ __launch_bounds__(256) void k_scatter_fsfd(
        const int* __restrict__ src, const int* __restrict__ dst,
        int* __restrict__ cursor, int* __restrict__ edge_src, int E, int g_scat,
        const float* __restrict__ h,
        const float* __restrict__ Ws, const float* __restrict__ bs,
        const float* __restrict__ Wd, const float* __restrict__ bd,
        float* __restrict__ fs, float* __restrict__ fd, int n, int g_gemm) {
    bool isA; int idx;
    role_split(blockIdx.x, g_scat, g_gemm, isA, idx);
    if (isA) {
        int e = idx * 256 + threadIdx.x;
        if (e < E) {
            int d = dst[e];
            int pos = atomicAdd(&cursor[d], 1);
            edge_src[pos] = src[e];
        }
        return;
    }
    __shared__ float WsL[64 * 64];
    __shared__ float WdL[64 * 64];
    fsfd_body(h, Ws, bs, Wd, bd, fs, fd, n, idx, WsL, WdL);
}

// standalone fsfd (layer 1)
__global__ __launch_bounds__(256) void k_fsfd(
        const float* __restrict__ h,
        const float* __restrict__ Ws, const float* __restrict__ bs,
        const float* __restrict__ Wd, const float* __restrict__ bd,
        float* __restrict__ fs, float* __restrict__ fd, int n) {
    __shared__ float WsL[64 * 64];
    __shared__ float WdL[64 * 64];
    fsfd_body(h, Ws, bs, Wd, bd, fs, fd, n, blockIdx.x, WsL, WdL);
}

// ---------------- GATv2 aggregate: one wave per dst node ----------------
// lane = head*16 + d. Edge ids are wave-uniform: readfirstlane -> SGPR so the
// fs-row address math is SALU + one 32-bit v_add (saddr-form gather).
__global__ __launch_bounds__(256) void k_agg(const float* __restrict__ fs,
                                             const float* __restrict__ fd,
                                             const float* __restrict__ attn,
                                             const int* __restrict__ row_ptr,
                                             const int* __restrict__ edge_src,
                                             float* __restrict__ hout, int n) {
    int wid = threadIdx.x >> 6;
    int node = blockIdx.x * 4 + wid;
    if (node >= n) return;
    int lane = threadIdx.x & 63;
    float a   = attn[lane];
    float fdv = fd[(size_t)node * 64 + lane];
    int s0 = __builtin_amdgcn_readfirstlane(row_ptr[node]);
    int s1 = __builtin_amdgcn_readfirstlane(row_ptr[node + 1]);
    float ssum = 0.f, acc = 0.f;
    for (int base = s0; base < s1; base += 8) {
        int ids[8];
#pragma unroll
        for (int k = 0; k < 8; ++k)
            ids[k] = edge_src[base + k];  // uniform addr; pad past E is zeroed
        float fv[8];
#pragma unroll
        for (int k = 0; k < 8; ++k) {
            unsigned sid = (unsigned)__builtin_amdgcn_readfirstlane(ids[k]);
            fv[k] = fs[(sid << 6) + (unsigned)lane];  // saddr + 32b voffset
        }
#pragma unroll
        for (int k = 0; k < 8; ++k) {
            float t = fv[k] + fdv;
            t = fmaxf(t, LRELU_SLOPE * t);  // leaky relu, branchless (slope<1)
            t *= a;
            t = reduce16(t);                // per-head sum, all lanes get it
            float p = __expf(t);
            p = (base + k < s1) ? p : 0.f;  // scalar-cond mask of tail dups
            ssum += p;
            acc = fmaf(p, fv[k], acc);
        }
    }
    float o = (s1 > s0) ? (acc / ssum) : 0.f;
    hout[(size_t)node * 64 + lane] = fmaxf(o, 0.f);
}

// ---------------- logits = h[N,64] @ W_out[64,2] + b_out ----------------
__global__ void k_out(const float* __restrict__ h, const float* __restrict__ Wo,
                      const float* __restrict__ bo, float* __restrict__ out, int n) {
    int i = blockIdx.x * 256 + threadIdx.x;
    if (i >= n * 2) return;
    int node = i >> 1, c = i & 1;
    const float* hr = h + (size_t)node * 64;
    float acc = bo[c];
#pragma unroll 8
    for (int k = 0; k < 64; ++k) acc += hr[k] * Wo[k * 2 + c];
    out[i] = acc;
}

extern "C" void kernel_launch(void* const* d_in, const int* in_sizes, int n_in,
                              void* d_out, int out_size, void* d_ws, size_t ws_size,
                              hipStream_t stream) {
    const float* feature  = (const float*)d_in[0];
    const int*   src      = (const int*)d_in[1];
    const int*   dst      = (const int*)d_in[2];
    const float* W_in     = (const float*)d_in[3];
    const float* b_in     = (const float*)d_in[4];
    const float* fc_src_W = (const float*)d_in[5];
    const float* fc_src_b = (const float*)d_in[6];
    const float* fc_dst_W = (const float*)d_in[7];
    const float* fc_dst_b = (const float*)d_in[8];
    const float* attn     = (const float*)d_in[9];
    const float* W_out    = (const float*)d_in[10];
    const float* b_out    = (const float*)d_in[11];
    float* out = (float*)d_out;

    const int N = in_sizes[0] / 128;  // 50000
    const int E = in_sizes[1];        // 800000
    const int nb = (N + 255) / 256;

    char* ws = (char*)d_ws;
    size_t off = 0;
    auto take = [&](size_t bytes) { char* p = ws + off; off = (off + bytes + 255) & ~(size_t)255; return p; };
    int*   deg        = (int*)take((size_t)N * 4);
    int*   row_ptr    = (int*)take((size_t)(N + 1) * 4);
    int*   cursor     = (int*)take((size_t)N * 4);
    int*   block_sums = (int*)take((size_t)nb * 4);
    int*   edge_src   = (int*)take((size_t)(E + 64) * 4);  // +64 pad for k_agg
    float* h          = (float*)take((size_t)N * 64 * 4);
    float* fs         = (float*)take((size_t)N * 64 * 4);
    float* fd         = (float*)take((size_t)N * 64 * 4);
    (void)ws_size; (void)n_in; (void)out_size;

    const int eb = (E + 255) / 256;           // 3125
    const int gemm_blocks = (N + 15) / 16;    // 3125
    const int agg_blocks  = (N + 3) / 4;

    hipMemsetAsync(deg, 0, (size_t)N * 4, stream);

    // hist || gemm_in  (independent chains fused; atomics hide behind VALU)
    k_hist_gemm<<<eb + gemm_blocks, 256, 0, stream>>>(
        dst, deg, E, eb, feature, W_in, b_in, h, N, gemm_blocks);

    k_scan1<<<nb, 256, 0, stream>>>(deg, cursor, block_sums, N);
    k_scan2<<<1, 256, 0, stream>>>(block_sums, nb);
    k_scan3<<<nb, 256, 0, stream>>>(cursor, block_sums, row_ptr, cursor, edge_src, N, E);

    // scatter || fsfd layer 0
    k_scatter_fsfd<<<eb + gemm_blocks, 256, 0, stream>>>(
        src, dst, cursor, edge_src, E, eb,
        h, fc_src_W, fc_src_b, fc_dst_W, fc_dst_b, fs, fd, N, gemm_blocks);

    k_agg<<<agg_blocks, 256, 0, stream>>>(fs, fd, attn, row_ptr, edge_src, h, N);

    k_fsfd<<<gemm_blocks, 256, 0, stream>>>(h, fc_src_W + 4096, fc_src_b + 64,
                                            fc_dst_W + 4096, fc_dst_b + 64, fs, fd, N);

    k_agg<<<agg_blocks, 256, 0, stream>>>(fs, fd, attn + 64, row_ptr, edge_src, h, N);

    k_out<<<(N * 2 + 255) / 256, 256, 0, stream>>>(h, W_out, b_out, out, N);
}

// Round 4
// 263.230 us; speedup vs baseline: 1.6790x; 1.0901x over previous
//
#include <hip/hip_runtime.h>

#define LRELU_SLOPE 0.2f

// ---------------- DPP helpers ----------------
template <int CTRL>
__device__ __forceinline__ float dpp_add(float x) {
    int xi = __float_as_int(x);
    int yi = __builtin_amdgcn_update_dpp(xi, xi, CTRL, 0xF, 0xF, false);
    return x + __int_as_float(yi);
}
// sum within each 16-lane row (every lane gets it)
__device__ __forceinline__ float reduce16(float t) {
    t = dpp_add<0x128>(t);  // row_ror:8
    t = dpp_add<0x124>(t);  // row_ror:4
    t = dpp_add<0x122>(t);  // row_ror:2
    t = dpp_add<0x121>(t);  // row_ror:1
    return t;
}
// sum within each 4-lane quad (every lane gets it): quad_perm [1,0,3,2], [2,3,0,1]
__device__ __forceinline__ float reduce_quad(float t) {
    t = dpp_add<0xB1>(t);
    t = dpp_add<0x4E>(t);
    return t;
}

// ---------------- block-wide exclusive scan helper (256 threads) -------------
__device__ __forceinline__ int block_excl_scan_256(int v, int* block_total) {
    int lane = threadIdx.x & 63;
    int wid  = threadIdx.x >> 6;
    int x = v;
#pragma unroll
    for (int off = 1; off < 64; off <<= 1) {
        int y = __shfl_up(x, off, 64);
        if (lane >= off) x += y;
    }
    __shared__ int wsum[4];
    if (lane == 63) wsum[wid] = x;
    __syncthreads();
    int t0 = wsum[0], t1 = wsum[1], t2 = wsum[2], t3 = wsum[3];
    int wofs = (wid > 0 ? t0 : 0) + (wid > 1 ? t1 : 0) + (wid > 2 ? t2 : 0);
    if (block_total) *block_total = t0 + t1 + t2 + t3;
    return wofs + x - v;  // exclusive
}

// role split for fused kernels: interleave A/B blocks by parity
__device__ __forceinline__ void role_split(int bid, int gA, int gB, bool& isA, int& idx) {
    int m = (gA < gB ? gA : gB) * 2;
    if (bid < m) { isA = (bid & 1) == 0; idx = bid >> 1; }
    else         { isA = (gA > gB);      idx = (m >> 1) + (bid - m); }
}

// ---------------- scans over 8-bucket degree arrays ----------------
__global__ void k_scan1(const int* __restrict__ deg_x, int* __restrict__ chunk_excl,
                        int* __restrict__ block_sums, int n) {
    int i = blockIdx.x * 256 + threadIdx.x;
    int v = 0;
    if (i < n) {
#pragma unroll
        for (int x = 0; x < 8; ++x) v += deg_x[x * n + i];
    }
    int total;
    int excl = block_excl_scan_256(v, &total);
    if (i < n) chunk_excl[i] = excl;
    if (threadIdx.x == 0) block_sums[blockIdx.x] = total;
}

// fused scan2+scan3: each block locally sums block_sums[0..b), then writes
// row_ptr and the 8 per-bucket cursors
__global__ void k_scan3(const int* __restrict__ chunk_excl, const int* __restrict__ bs,
                        const int* __restrict__ deg_x,
                        int* __restrict__ row_ptr, int* __restrict__ cursor_x,
                        int* __restrict__ edge_src, int n, int E, int nb) {
    int t = threadIdx.x;
    int v = (t < blockIdx.x && t < nb) ? bs[t] : 0;
    int total;
    (void)block_excl_scan_256(v, &total);  // total = sum over t<blockIdx.x
    int i = blockIdx.x * 256 + threadIdx.x;
    if (i < n) {
        int r = chunk_excl[i] + total;
        row_ptr[i] = r;
        int cum = r;
#pragma unroll
        for (int x = 0; x < 8; ++x) { cursor_x[x * n + i] = cum; cum += deg_x[x * n + i]; }
    }
    if (blockIdx.x == 0 && threadIdx.x == 0) row_ptr[n] = E;
    if (blockIdx.x == 0 && threadIdx.x < 64) edge_src[E + threadIdx.x] = 0;
}

// ---------------- FUSED: bucketed hist (atomics) + gemm_in (VALU) ------------
__global__ __launch_bounds__(256) void k_hist_gemm(
        const int* __restrict__ dst, int* __restrict__ deg_x, int E, int g_hist,
        const float* __restrict__ feat, const float* __restrict__ W,
        const float* __restrict__ b, float* __restrict__ h, int n, int g_gemm) {
    bool isA; int idx;
    role_split(blockIdx.x, g_hist, g_gemm, isA, idx);
    if (isA) {
        int e = idx * 256 + threadIdx.x;
        if (e < E) {
            int bkt = (idx * 2) & 7;  // = global blockIdx %8 under parity interleave
            atomicAdd(&deg_x[bkt * n + dst[e]], 1);
        }
        return;
    }
    __shared__ float WL[128 * 64];
    {
        float4* WL4 = (float4*)WL;
        const float4* W4 = (const float4*)W;
        for (int i = threadIdx.x; i < 128 * 64 / 4; i += 256) WL4[i] = W4[i];
    }
    __syncthreads();
    int node = idx * 16 + (threadIdx.x >> 4);
    int cg = (threadIdx.x & 15) * 4;
    if (node >= n) return;
    const float4* fr4 = (const float4*)(feat + (size_t)node * 128);
    float4 acc = *(const float4*)(b + cg);
#pragma unroll 4
    for (int k4 = 0; k4 < 32; ++k4) {
        float4 f = fr4[k4];
        const float* wp = WL + (k4 * 4) * 64 + cg;
        float4 w0 = *(const float4*)(wp);
        float4 w1 = *(const float4*)(wp + 64);
        float4 w2 = *(const float4*)(wp + 128);
        float4 w3 = *(const float4*)(wp + 192);
        acc.x += f.x * w0.x + f.y * w1.x + f.z * w2.x + f.w * w3.x;
        acc.y += f.x * w0.y + f.y * w1.y + f.z * w2.y + f.w * w3.y;
        acc.z += f.x * w0.z + f.y * w1.z + f.z * w2.z + f.w * w3.z;
        acc.w += f.x * w0.w + f.y * w1.w + f.z * w2.w + f.w * w3.w;
    }
    *(float4*)(h + (size_t)node * 64 + cg) = acc;
}

// fsfd inner body
__device__ __forceinline__ void fsfd_body(
        const float* __restrict__ h,
        const float* __restrict__ Ws, const float* __restrict__ bs,
        const float* __restrict__ Wd, const float* __restrict__ bd,
        float* __restrict__ fs, float* __restrict__ fd, int n, int idx,
        float* WsL, float* WdL) {
    {
        float4* s4 = (float4*)WsL; float4* d4 = (float4*)WdL;
        const float4* Ws4 = (const float4*)Ws; const float4* Wd4 = (const float4*)Wd;
        for (int i = threadIdx.x; i < 64 * 64 / 4; i += 256) { s4[i] = Ws4[i]; d4[i] = Wd4[i]; }
    }
    __syncthreads();
    int node = idx * 16 + (threadIdx.x >> 4);
    int cg = (threadIdx.x & 15) * 4;
    if (node >= n) return;
    const float4* hr4 = (const float4*)(h + (size_t)node * 64);
    float4 aS = *(const float4*)(bs + cg);
    float4 aD = *(const float4*)(bd + cg);
#pragma unroll 4
    for (int k4 = 0; k4 < 16; ++k4) {
        float4 f = hr4[k4];
        const float* sp = WsL + (k4 * 4) * 64 + cg;
        const float* dp = WdL + (k4 * 4) * 64 + cg;
        float4 s0 = *(const float4*)(sp);
        float4 s1 = *(const float4*)(sp + 64);
        float4 s2 = *(const float4*)(sp + 128);
        float4 s3 = *(const float4*)(sp + 192);
        float4 d0 = *(const float4*)(dp);
        float4 d1 = *(const float4*)(dp + 64);
        float4 d2 = *(const float4*)(dp + 128);
        float4 d3 = *(const float4*)(dp + 192);
        aS.x += f.x * s0.x + f.y * s1.x + f.z * s2.x + f.w * s3.x;
        aS.y += f.x * s0.y + f.y * s1.y + f.z * s2.y + f.w * s3.y;
        aS.z += f.x * s0.z + f.y * s1.z + f.z * s2.z + f.w * s3.z;
        aS.w += f.x * s0.w + f.y * s1.w + f.z * s2.w + f.w * s3.w;
        aD.x += f.x * d0.x + f.y * d1.x + f.z * d2.x + f.w * d3.x;
        aD.y += f.x * d0.y + f.y * d1.y + f.z * d2.y + f.w * d3.y;
        aD.z += f.x * d0.z + f.y * d1.z + f.z * d2.z + f.w * d3.z;
        aD.w += f.x * d0.w + f.y * d1.w + f.z * d2.w + f.w * d3.w;
    }
    *(float4*)(fs + (size_t)node * 64 + cg) = aS;
    *(float4*)(fd + (size_t)node * 64 + cg) = aD;
}

// ---------------- FUSED: bucketed scatter + fsfd layer 0 ----------------
__global__ __launch_bounds__(256) void k_scatter_fsfd(
        const int* __restrict__ src, const int* __restrict__ dst,
        int* __restrict__ cursor_x, int* __restrict__ edge_src, int E, int g_scat,
        const float* __restrict__ h,
        const float* __restrict__ Ws, const float* __restrict__ bs,
        const float* __restrict__ Wd, const float* __restrict__ bd,
        float* __restrict__ fs, float* __restrict__ fd, int n, int g_gemm) {
    bool isA; int idx;
    role_split(blockIdx.x, g_scat, g_gemm, isA, idx);
    if (isA) {
        int e = idx * 256 + threadIdx.x;
        if (e < E) {
            int bkt = (idx * 2) & 7;  // must match k_hist_gemm's bucket(e)
            int d = dst[e];
            int pos = atomicAdd(&cursor_x[bkt * n + d], 1);
            edge_src[pos] = src[e];
        }
        return;
    }
    __shared__ float WsL[64 * 64];
    __shared__ float WdL[64 * 64];
    fsfd_body(h, Ws, bs, Wd, bd, fs, fd, n, idx, WsL, WdL);
}

// standalone fsfd (layer 1)
__global__ __launch_bounds__(256) void k_fsfd(
        const float* __restrict__ h,
        const float* __restrict__ Ws, const float* __restrict__ bs,
        const float* __restrict__ Wd, const float* __restrict__ bd,
        float* __restrict__ fs, float* __restrict__ fd, int n) {
    __shared__ float WsL[64 * 64];
    __shared__ float WdL[64 * 64];
    fsfd_body(h, Ws, bs, Wd, bd, fs, fd, n, blockIdx.x, WsL, WdL);
}

// ---------------- GATv2 aggregate ----------------
// wave = 1 node; 4 edge-slots x 16 lanes; lane holds float4 of the 64-f row.
// Gather is one dwordx4/edge-slot; head-dot folded into attn dot; per-head
// reduce = 2 quad_perm DPP adds; cross-slot merge once per node.
__device__ __forceinline__ void edge_accum(float4 fv, float4 fdv, float4 a4,
                                           bool valid, float& ssum, float4& acc) {
    float tx = fv.x + fdv.x;
    float ty = fv.y + fdv.y;
    float tz = fv.z + fdv.z;
    float tw = fv.w + fdv.w;
    tx = fmaxf(tx, LRELU_SLOPE * tx);
    ty = fmaxf(ty, LRELU_SLOPE * ty);
    tz = fmaxf(tz, LRELU_SLOPE * tz);
    tw = fmaxf(tw, LRELU_SLOPE * tw);
    float s = tx * a4.x;
    s = fmaf(ty, a4.y, s);
    s = fmaf(tz, a4.z, s);
    s = fmaf(tw, a4.w, s);
    s = reduce_quad(s);            // per-head score (quad = one head of one slot)
    float p = valid ? __expf(s) : 0.f;
    ssum += p;
    acc.x = fmaf(p, fv.x, acc.x);
    acc.y = fmaf(p, fv.y, acc.y);
    acc.z = fmaf(p, fv.z, acc.z);
    acc.w = fmaf(p, fv.w, acc.w);
}

template <bool FUSE_OUT>
__global__ __launch_bounds__(256) void k_agg(
        const float4* __restrict__ fs4, const float4* __restrict__ fd4,
        const float4* __restrict__ attn4,        // 16 float4 (this layer)
        const int* __restrict__ row_ptr, const int* __restrict__ edge_src,
        float4* __restrict__ hout4,              // layer 0 output
        const float4* __restrict__ Wo4,          // layer 1: W_out as float4[32]
        const float* __restrict__ bo, float2* __restrict__ outp, int n) {
    int wid = threadIdx.x >> 6;
    int node = blockIdx.x * 4 + wid;
    if (node >= n) return;
    int lane = threadIdx.x & 63;
    int slot = lane >> 4;
    int sl   = lane & 15;
    float4 a4  = attn4[sl];
    float4 fdv = fd4[node * 16 + sl];
    int s0 = __builtin_amdgcn_readfirstlane(row_ptr[node]);
    int s1 = __builtin_amdgcn_readfirstlane(row_ptr[node + 1]);
    float4 acc = {0.f, 0.f, 0.f, 0.f};
    float ssum = 0.f;
    for (int base = s0; base < s1; base += 8) {
        int id0 = edge_src[base + slot];
        int id1 = edge_src[base + 4 + slot];
        float4 f0 = fs4[(size_t)(unsigned)id0 * 16 + sl];
        float4 f1 = fs4[(size_t)(unsigned)id1 * 16 + sl];
        edge_accum(f0, fdv, a4, base + slot < s1,     ssum, acc);
        edge_accum(f1, fdv, a4, base + 4 + slot < s1, ssum, acc);
    }
    // merge the 4 edge-slots (lanes ^16, ^32)
    acc.x += __shfl_xor(acc.x, 16); acc.x += __shfl_xor(acc.x, 32);
    acc.y += __shfl_xor(acc.y, 16); acc.y += __shfl_xor(acc.y, 32);
    acc.z += __shfl_xor(acc.z, 16); acc.z += __shfl_xor(acc.z, 32);
    acc.w += __shfl_xor(acc.w, 16); acc.w += __shfl_xor(acc.w, 32);
    ssum  += __shfl_xor(ssum, 16);  ssum  += __shfl_xor(ssum, 32);
    float inv = (s1 > s0) ? 1.f / ssum : 0.f;
    float4 o;
    o.x = fmaxf(acc.x * inv, 0.f);
    o.y = fmaxf(acc.y * inv, 0.f);
    o.z = fmaxf(acc.z * inv, 0.f);
    o.w = fmaxf(acc.w * inv, 0.f);
    if (!FUSE_OUT) {
        if (slot == 0) hout4[node * 16 + sl] = o;
    } else {
        // out[node] = o(64) @ W_out(64x2) + b_out, reduced across sl=0..15
        float4 wA = Wo4[sl * 2 + 0];  // rows 4sl,4sl+1: {w00,w01,w10,w11}
        float4 wB = Wo4[sl * 2 + 1];  // rows 4sl+2,4sl+3
        float c0 = o.x * wA.x + o.y * wA.z + o.z * wB.x + o.w * wB.z;
        float c1 = o.x * wA.y + o.y * wA.w + o.z * wB.y + o.w * wB.w;
        c0 = reduce16(c0);
        c1 = reduce16(c1);
        if (lane == 0) {
            float2 r; r.x = c0 + bo[0]; r.y = c1 + bo[1];
            outp[node] = r;
        }
    }
}

extern "C" void kernel_launch(void* const* d_in, const int* in_sizes, int n_in,
                              void* d_out, int out_size, void* d_ws, size_t ws_size,
                              hipStream_t stream) {
    const float* feature  = (const float*)d_in[0];
    const int*   src      = (const int*)d_in[1];
    const int*   dst      = (const int*)d_in[2];
    const float* W_in     = (const float*)d_in[3];
    const float* b_in     = (const float*)d_in[4];
    const float* fc_src_W = (const float*)d_in[5];
    const float* fc_src_b = (const float*)d_in[6];
    const float* fc_dst_W = (const float*)d_in[7];
    const float* fc_dst_b = (const float*)d_in[8];
    const float* attn     = (const float*)d_in[9];
    const float* W_out    = (const float*)d_in[10];
    const float* b_out    = (const float*)d_in[11];

    const int N = in_sizes[0] / 128;  // 50000
    const int E = in_sizes[1];        // 800000
    const int nb = (N + 255) / 256;   // 196

    char* ws = (char*)d_ws;
    size_t off = 0;
    auto take = [&](size_t bytes) { char* p = ws + off; off = (off + bytes + 255) & ~(size_t)255; return p; };
    int*   deg_x      = (int*)take((size_t)N * 8 * 4);
    int*   cursor_x   = (int*)take((size_t)N * 8 * 4);
    int*   chunk_excl = (int*)take((size_t)N * 4);
    int*   row_ptr    = (int*)take((size_t)(N + 1) * 4);
    int*   block_sums = (int*)take((size_t)nb * 4);
    int*   edge_src   = (int*)take((size_t)(E + 64) * 4);
    float* h          = (float*)take((size_t)N * 64 * 4);
    float* fs         = (float*)take((size_t)N * 64 * 4);
    float* fd         = (float*)take((size_t)N * 64 * 4);
    (void)ws_size; (void)n_in; (void)out_size;

    const int eb = (E + 255) / 256;           // 3125
    const int gemm_blocks = (N + 15) / 16;    // 3125
    const int agg_blocks  = (N + 3) / 4;

    hipMemsetAsync(deg_x, 0, (size_t)N * 8 * 4, stream);

    // bucketed hist || gemm_in
    k_hist_gemm<<<eb + gemm_blocks, 256, 0, stream>>>(
        dst, deg_x, E, eb, feature, W_in, b_in, h, N, gemm_blocks);

    k_scan1<<<nb, 256, 0, stream>>>(deg_x, chunk_excl, block_sums, N);
    k_scan3<<<nb, 256, 0, stream>>>(chunk_excl, block_sums, deg_x,
                                    row_ptr, cursor_x, edge_src, N, E, nb);

    // bucketed scatter || fsfd layer 0
    k_scatter_fsfd<<<eb + gemm_blocks, 256, 0, stream>>>(
        src, dst, cursor_x, edge_src, E, eb,
        h, fc_src_W, fc_src_b, fc_dst_W, fc_dst_b, fs, fd, N, gemm_blocks);

    // layer 0 aggregate -> h
    k_agg<false><<<agg_blocks, 256, 0, stream>>>(
        (const float4*)fs, (const float4*)fd, (const float4*)attn,
        row_ptr, edge_src, (float4*)h, nullptr, nullptr, nullptr, N);

    // layer 1 projections
    k_fsfd<<<gemm_blocks, 256, 0, stream>>>(h, fc_src_W + 4096, fc_src_b + 64,
                                            fc_dst_W + 4096, fc_dst_b + 64, fs, fd, N);

    // layer 1 aggregate + output projection fused
    k_agg<true><<<agg_blocks, 256, 0, stream>>>(
        (const float4*)fs, (const float4*)fd, (const float4*)(attn + 64),
        row_ptr, edge_src, nullptr, (const float4*)W_out, b_out, (float2*)d_out, N);
}